// Round 4
// baseline (251.916 us; speedup 1.0000x reference)
//
#include <hip/hip_runtime.h>
#include <hip/hip_bf16.h>

// ---------------- problem constants (fixed by setup_inputs) ----------------
constexpr int B_  = 8;
constexpr int H_  = 64;
constexpr int W_  = 64;
constexpr int C_  = 192;
constexpr int Dn  = 192;
constexpr int Nst = 8;    // state dim N
constexpr int R_  = 12;
constexpr int K_  = 4;    // directions
constexpr int L_  = H_ * W_;          // 4096
constexpr int CS  = 64;               // scan chunk size
constexpr int NC  = L_ / CS;          // 64 chunks
constexpr int CPROJ = R_ + 2 * Nst;   // 28 proj outputs per direction
constexpr int MROWS = B_ * L_;        // 32768

typedef __attribute__((ext_vector_type(8))) short short8v;
typedef __attribute__((ext_vector_type(4))) float f32x4;

// t -> spatial position for direction k (verified round 0)
__device__ __forceinline__ int map_t(int k, int t) {
    int tt = (k >= 2) ? (L_ - 1 - t) : t;
    if (k & 1) tt = (tt & 63) * 64 + (tt >> 6);
    return tt;
}

__device__ __forceinline__ short f2bf(float f) {   // round-to-nearest-even
    unsigned u = __float_as_uint(f);
    u += 0x7FFFu + ((u >> 16) & 1u);
    return (short)(u >> 16);
}
__device__ __forceinline__ float bf2f(short s) {
    return __uint_as_float(((unsigned)(unsigned short)s) << 16);
}

// ---------------- fused f32 -> bf16 convert (x and all weights) -------------
constexpr int WOFF_IN  = 0;               // w_in  (384x192)
constexpr int WOFF_XP  = 73728;           // xpw   (112x192)
constexpr int WOFF_OUT = 95232;           // wout  (192x192)
constexpr int WTOTAL   = 132096;
constexpr int XUNITS   = MROWS * Dn / 8;  // 786432 groups of 8
constexpr int WUNITS   = WTOTAL / 8;      // 16512
__global__ __launch_bounds__(256) void k_cvt(const float* __restrict__ x,
                                             const float* __restrict__ w_in,
                                             const float* __restrict__ xpw,
                                             const float* __restrict__ wout,
                                             short* __restrict__ x_bf,
                                             short* __restrict__ w_bf) {
    int g = blockIdx.x * 256 + threadIdx.x;
    const float* src;
    short* dst;
    int off;
    if (g < XUNITS) { src = x; dst = x_bf; off = g * 8; }
    else {
        g -= XUNITS;
        if (g >= WUNITS) return;
        int base = g * 8;
        dst = w_bf; off = base;
        if (base < WOFF_XP)       { src = w_in; }
        else if (base < WOFF_OUT) { src = xpw;  src -= WOFF_XP; }
        else                      { src = wout; src -= WOFF_OUT; }
    }
    float4 a = *reinterpret_cast<const float4*>(src + off);
    float4 b = *reinterpret_cast<const float4*>(src + off + 4);
    short8v v = {f2bf(a.x), f2bf(a.y), f2bf(a.z), f2bf(a.w),
                 f2bf(b.x), f2bf(b.y), f2bf(b.z), f2bf(b.w)};
    *reinterpret_cast<short8v*>(dst + off) = v;
}

// ---------------- bf16 MFMA GEMM cores --------------------------------------
// A (M x K) bf16 row-major, W (Nact x K) bf16 row-major. 128x64 tile, 4 waves.
// 16x16x32 frag: operand elem j of lane l -> row=l&15, k=(l>>4)*8+j (one
// contiguous short8). D: col=l&15, row=(l>>4)*4+r.
__device__ __forceinline__ void mgemm_core(const short* __restrict__ A,
                                           const short* __restrict__ Wb,
                                           f32x4 (&acc)[4][2],
                                           int mrow, int ncol, int Nact, int K) {
    const int lane = threadIdx.x & 63;
    const int koff = (lane >> 4) * 8;
    for (int k0 = 0; k0 < K; k0 += 32) {
        short8v af[4], bfr[2];
#pragma unroll
        for (int mf = 0; mf < 4; mf++)
            af[mf] = *reinterpret_cast<const short8v*>(
                A + (size_t)(mrow + mf * 16) * K + k0 + koff);
#pragma unroll
        for (int nf = 0; nf < 2; nf++) {
            int r = ncol + nf * 16;
            short8v z = {0, 0, 0, 0, 0, 0, 0, 0};
            bfr[nf] = (r < Nact)
                ? *reinterpret_cast<const short8v*>(Wb + (size_t)r * K + k0 + koff)
                : z;
        }
#pragma unroll
        for (int mf = 0; mf < 4; mf++)
#pragma unroll
            for (int nf = 0; nf < 2; nf++)
                acc[mf][nf] = __builtin_amdgcn_mfma_f32_16x16x32_bf16(
                    af[mf], bfr[nf], acc[mf][nf], 0, 0, 0);
    }
}

// f32-output GEMM (x_proj, out_proj)
__global__ __launch_bounds__(256) void k_mgemm_f(const short* __restrict__ A,
                                                 const short* __restrict__ Wb,
                                                 float* __restrict__ out0,
                                                 int Nact, int K) {
    const int m0 = blockIdx.x * 128, n0 = blockIdx.y * 64;
    const int wid = threadIdx.x >> 6, lane = threadIdx.x & 63;
    const int wm = wid >> 1, wn = wid & 1;
    f32x4 acc[4][2] = {};
    mgemm_core(A, Wb, acc, m0 + wm * 64 + (lane & 15), n0 + wn * 32 + (lane & 15),
               Nact, K);
    const int prow = (lane >> 4) * 4, pcol = lane & 15;
#pragma unroll
    for (int mf = 0; mf < 4; mf++) {
        int mbase = m0 + wm * 64 + mf * 16 + prow;
#pragma unroll
        for (int nf = 0; nf < 2; nf++) {
            int n = n0 + wn * 32 + nf * 16 + pcol;
            if (n >= Nact) continue;
#pragma unroll
            for (int r = 0; r < 4; r++)
                out0[(size_t)(mbase + r) * Nact + n] = acc[mf][nf][r];
        }
    }
}

// in_proj: split bf16 outputs (xf | z), each ldc=192
__global__ __launch_bounds__(256) void k_mgemm_in(const short* __restrict__ A,
                                                  const short* __restrict__ Wb,
                                                  short* __restrict__ xf_bf,
                                                  short* __restrict__ z_bf,
                                                  int K) {
    const int m0 = blockIdx.x * 128, n0 = blockIdx.y * 64;
    const int wid = threadIdx.x >> 6, lane = threadIdx.x & 63;
    const int wm = wid >> 1, wn = wid & 1;
    f32x4 acc[4][2] = {};
    mgemm_core(A, Wb, acc, m0 + wm * 64 + (lane & 15), n0 + wn * 32 + (lane & 15),
               384, K);
    const int prow = (lane >> 4) * 4, pcol = lane & 15;
#pragma unroll
    for (int mf = 0; mf < 4; mf++) {
        int mbase = m0 + wm * 64 + mf * 16 + prow;
#pragma unroll
        for (int nf = 0; nf < 2; nf++) {
            int n = n0 + wn * 32 + nf * 16 + pcol;
#pragma unroll
            for (int r = 0; r < 4; r++) {
                int m = mbase + r;
                if (n < 192) xf_bf[(size_t)m * 192 + n] = f2bf(acc[mf][nf][r]);
                else         z_bf[(size_t)m * 192 + (n - 192)] = f2bf(acc[mf][nf][r]);
            }
        }
    }
}

// ---------------- depthwise 3x3 conv + bias + SiLU (bf16 in/out) ------------
__global__ __launch_bounds__(256) void k_conv(const short* __restrict__ xfb,
                                              const float* __restrict__ cw,
                                              const float* __restrict__ cb,
                                              short* __restrict__ xcb) {
    size_t i = (size_t)blockIdx.x * 256 + threadIdx.x;  // over B*H*W*Dn
    int d = (int)(i % Dn);
    int p = (int)(i / Dn);
    int w = p & 63; p >>= 6;
    int h = p & 63; p >>= 6;
    int b = p;
    float acc = cb[d];
#pragma unroll
    for (int kh = 0; kh < 3; kh++) {
        int hh = h + kh - 1;
        if (hh < 0 || hh >= H_) continue;
#pragma unroll
        for (int kw = 0; kw < 3; kw++) {
            int ww = w + kw - 1;
            if (ww < 0 || ww >= W_) continue;
            acc = fmaf(bf2f(xfb[(((size_t)b * H_ + hh) * W_ + ww) * Dn + d]),
                       cw[d * 9 + kh * 3 + kw], acc);
        }
    }
    float sig = 1.f / (1.f + __expf(-acc));
    xcb[i] = f2bf(acc * sig);
}

// ---------------- per-step delta / e1 helper --------------------------------
// x = dt pre-activation. delta = softplus(x); e1 = exp(-delta) = 1/(1+e^x).
__device__ __forceinline__ void delta_e1(float x, float& delta, float& e1) {
    if (x > 20.f) { delta = x; e1 = __expf(-x); }
    else {
        float t = __expf(x);
        delta = __logf(1.f + t);
        e1 = __builtin_amdgcn_rcpf(1.f + t);
    }
}

__device__ __forceinline__ float dot12(const float4& a, const float4& b,
                                       const float4& c, const float* w, float x) {
    x = fmaf(a.x, w[0], x);  x = fmaf(a.y, w[1], x);
    x = fmaf(a.z, w[2], x);  x = fmaf(a.w, w[3], x);
    x = fmaf(b.x, w[4], x);  x = fmaf(b.y, w[5], x);
    x = fmaf(b.z, w[6], x);  x = fmaf(b.w, w[7], x);
    x = fmaf(c.x, w[8], x);  x = fmaf(c.y, w[9], x);
    x = fmaf(c.z, w[10], x); x = fmaf(c.w, w[11], x);
    return x;
}

// ---------------- scan phase 1: per-chunk (prod(a), h_partial) --------------
// LDS holds per-step [dt(12) | B(8)] = 5 float4 (C not consumed here).
__global__ __launch_bounds__(192) void k_scan1(const short* __restrict__ xcb,
                                               const float* __restrict__ xdbl,
                                               const float* __restrict__ dtw_all,
                                               const float* __restrict__ dtb_all,
                                               const float* __restrict__ alog,
                                               float* __restrict__ Aprod,
                                               float* __restrict__ hpart) {
    const int blk = blockIdx.x;            // ((b*K + k)*NC + c)
    const int c = blk % NC;
    const int k = (blk / NC) % K_;
    const int b = blk / (NC * K_);
    const int d = threadIdx.x;
    const int t0 = c * CS;

    __shared__ float4 sx4[CS][5];
    const float4* xd4 = reinterpret_cast<const float4*>(xdbl);
    for (int i = d; i < CS * 5; i += 192) {
        int ts = i / 5, q = i % 5;
        sx4[ts][q] = xd4[((size_t)b * L_ + map_t(k, t0 + ts)) * 28 + k * 7 + q];
    }
    __syncthreads();

    float dtw[R_];
#pragma unroll
    for (int r = 0; r < R_; r++) dtw[r] = dtw_all[((size_t)k * Dn + d) * R_ + r];
    const float bias = dtb_all[k * Dn + d];
    float Av[Nst];
    bool fast = true;
#pragma unroll
    for (int n = 0; n < Nst; n++) {
        Av[n] = -__expf(alog[((size_t)k * Dn + d) * Nst + n]);
        fast = fast && (fabsf(Av[n] + (float)(n + 1)) < 1e-3f);
    }

    float h[Nst] = {};
    float Ap[Nst];
#pragma unroll
    for (int n = 0; n < Nst; n++) Ap[n] = 1.f;
    float e1p = 1.f;

    float u_next = bf2f(xcb[((size_t)b * L_ + map_t(k, t0)) * Dn + d]);
    if (fast) {
        for (int ts = 0; ts < CS; ts++) {
            float u = u_next;
            if (ts + 1 < CS) u_next = bf2f(xcb[((size_t)b * L_ + map_t(k, t0 + ts + 1)) * Dn + d]);
            float4 q0 = sx4[ts][0], q1 = sx4[ts][1], q2 = sx4[ts][2];
            float4 qb0 = sx4[ts][3], qb1 = sx4[ts][4];
            float delta, e1; delta_e1(dot12(q0, q1, q2, dtw, bias), delta, e1);
            float du = delta * u;
            e1p *= e1;
            float a2 = e1 * e1, a3 = a2 * e1, a4 = a2 * a2;
            float a5 = a4 * e1, a6 = a4 * a2, a7 = a4 * a3, a8 = a4 * a4;
            h[0] = fmaf(e1, h[0], du * qb0.x);
            h[1] = fmaf(a2, h[1], du * qb0.y);
            h[2] = fmaf(a3, h[2], du * qb0.z);
            h[3] = fmaf(a4, h[3], du * qb0.w);
            h[4] = fmaf(a5, h[4], du * qb1.x);
            h[5] = fmaf(a6, h[5], du * qb1.y);
            h[6] = fmaf(a7, h[6], du * qb1.z);
            h[7] = fmaf(a8, h[7], du * qb1.w);
        }
        float p2 = e1p * e1p, p3 = p2 * e1p, p4 = p2 * p2;
        Ap[0] = e1p; Ap[1] = p2; Ap[2] = p3; Ap[3] = p4;
        Ap[4] = p4 * e1p; Ap[5] = p4 * p2; Ap[6] = p4 * p3; Ap[7] = p4 * p4;
    } else {
        for (int ts = 0; ts < CS; ts++) {
            float u = u_next;
            if (ts + 1 < CS) u_next = bf2f(xcb[((size_t)b * L_ + map_t(k, t0 + ts + 1)) * Dn + d]);
            float4 q0 = sx4[ts][0], q1 = sx4[ts][1], q2 = sx4[ts][2];
            float4 qb0 = sx4[ts][3], qb1 = sx4[ts][4];
            float Bv[Nst] = {qb0.x, qb0.y, qb0.z, qb0.w, qb1.x, qb1.y, qb1.z, qb1.w};
            float delta, e1; delta_e1(dot12(q0, q1, q2, dtw, bias), delta, e1);
            float du = delta * u;
#pragma unroll
            for (int n = 0; n < Nst; n++) {
                float a = __expf(delta * Av[n]);
                Ap[n] *= a;
                h[n] = fmaf(a, h[n], du * Bv[n]);
            }
        }
    }
    size_t base = ((((size_t)(b * K_ + k) * NC + c) * Dn + d)) * Nst;
#pragma unroll
    for (int n = 0; n < Nst; n++) { Aprod[base + n] = Ap[n]; hpart[base + n] = h[n]; }
}

// ---------------- scan phase 2: chunk-level recurrence -----------------------
__global__ __launch_bounds__(256) void k_scan2(const float* __restrict__ Aprod,
                                               const float* __restrict__ hpart,
                                               float* __restrict__ hin) {
    int idx = blockIdx.x * 256 + threadIdx.x;   // B*K*Dn*Nst = 49152
    int dn = idx % (Dn * Nst);
    int bk = idx / (Dn * Nst);
    size_t stride = (size_t)Dn * Nst;
    size_t base = (size_t)bk * NC * stride + dn;
    float h = 0.f;
    for (int cc = 0; cc < NC; cc++) {
        size_t s = base + (size_t)cc * stride;
        hin[s] = h;
        h = fmaf(Aprod[s], h, hpart[s]);
    }
}

// ---------------- scan phase 3: recompute with h_in, emit y (plain store) ---
// LDS holds per-step [dt(12) | B(8) | C(8)] = 7 float4.
__global__ __launch_bounds__(192) void k_scan3(const short* __restrict__ xcb,
                                               const float* __restrict__ xdbl,
                                               const float* __restrict__ dtw_all,
                                               const float* __restrict__ dtb_all,
                                               const float* __restrict__ alog,
                                               const float* __restrict__ dvec,
                                               const float* __restrict__ hin,
                                               short* __restrict__ y0,
                                               short* __restrict__ y1,
                                               short* __restrict__ y2,
                                               short* __restrict__ y3) {
    const int blk = blockIdx.x;
    const int c = blk % NC;
    const int k = (blk / NC) % K_;
    const int b = blk / (NC * K_);
    const int d = threadIdx.x;
    const int t0 = c * CS;
    short* __restrict__ yk = (k == 0) ? y0 : (k == 1) ? y1 : (k == 2) ? y2 : y3;

    __shared__ float4 sx4[CS][7];
    const float4* xd4 = reinterpret_cast<const float4*>(xdbl);
    for (int i = d; i < CS * 7; i += 192) {
        int ts = i / 7, q = i % 7;
        sx4[ts][q] = xd4[((size_t)b * L_ + map_t(k, t0 + ts)) * 28 + k * 7 + q];
    }
    __syncthreads();

    float dtw[R_];
#pragma unroll
    for (int r = 0; r < R_; r++) dtw[r] = dtw_all[((size_t)k * Dn + d) * R_ + r];
    const float bias = dtb_all[k * Dn + d];
    const float Dk = dvec[k * Dn + d];
    float Av[Nst];
    bool fast = true;
#pragma unroll
    for (int n = 0; n < Nst; n++) {
        Av[n] = -__expf(alog[((size_t)k * Dn + d) * Nst + n]);
        fast = fast && (fabsf(Av[n] + (float)(n + 1)) < 1e-3f);
    }

    size_t hbase = ((((size_t)(b * K_ + k) * NC + c) * Dn + d)) * Nst;
    float h[Nst];
#pragma unroll
    for (int n = 0; n < Nst; n++) h[n] = hin[hbase + n];

    int lm = map_t(k, t0);
    float u_next = bf2f(xcb[((size_t)b * L_ + lm) * Dn + d]);
    if (fast) {
        for (int ts = 0; ts < CS; ts++) {
            int lm_cur = lm;
            float u = u_next;
            if (ts + 1 < CS) {
                lm = map_t(k, t0 + ts + 1);
                u_next = bf2f(xcb[((size_t)b * L_ + lm) * Dn + d]);
            }
            float4 q0 = sx4[ts][0], q1 = sx4[ts][1], q2 = sx4[ts][2];
            float4 qb0 = sx4[ts][3], qb1 = sx4[ts][4];
            float4 qc0 = sx4[ts][5], qc1 = sx4[ts][6];
            float delta, e1; delta_e1(dot12(q0, q1, q2, dtw, bias), delta, e1);
            float du = delta * u;
            float a2 = e1 * e1, a3 = a2 * e1, a4 = a2 * a2;
            float a5 = a4 * e1, a6 = a4 * a2, a7 = a4 * a3, a8 = a4 * a4;
            h[0] = fmaf(e1, h[0], du * qb0.x);
            h[1] = fmaf(a2, h[1], du * qb0.y);
            h[2] = fmaf(a3, h[2], du * qb0.z);
            h[3] = fmaf(a4, h[3], du * qb0.w);
            h[4] = fmaf(a5, h[4], du * qb1.x);
            h[5] = fmaf(a6, h[5], du * qb1.y);
            h[6] = fmaf(a7, h[6], du * qb1.z);
            h[7] = fmaf(a8, h[7], du * qb1.w);
            float y = h[0] * qc0.x;
            y = fmaf(h[1], qc0.y, y);
            y = fmaf(h[2], qc0.z, y);
            y = fmaf(h[3], qc0.w, y);
            y = fmaf(h[4], qc1.x, y);
            y = fmaf(h[5], qc1.y, y);
            y = fmaf(h[6], qc1.z, y);
            y = fmaf(h[7], qc1.w, y);
            yk[((size_t)b * L_ + lm_cur) * Dn + d] = f2bf(fmaf(Dk, u, y));
        }
    } else {
        for (int ts = 0; ts < CS; ts++) {
            int lm_cur = lm;
            float u = u_next;
            if (ts + 1 < CS) {
                lm = map_t(k, t0 + ts + 1);
                u_next = bf2f(xcb[((size_t)b * L_ + lm) * Dn + d]);
            }
            float4 q0 = sx4[ts][0], q1 = sx4[ts][1], q2 = sx4[ts][2];
            float4 qb0 = sx4[ts][3], qb1 = sx4[ts][4];
            float4 qc0 = sx4[ts][5], qc1 = sx4[ts][6];
            float Bv[Nst] = {qb0.x, qb0.y, qb0.z, qb0.w, qb1.x, qb1.y, qb1.z, qb1.w};
            float Cv[Nst] = {qc0.x, qc0.y, qc0.z, qc0.w, qc1.x, qc1.y, qc1.z, qc1.w};
            float delta, e1; delta_e1(dot12(q0, q1, q2, dtw, bias), delta, e1);
            float du = delta * u;
            float y = 0.f;
#pragma unroll
            for (int n = 0; n < Nst; n++) {
                float a = __expf(delta * Av[n]);
                h[n] = fmaf(a, h[n], du * Bv[n]);
                y = fmaf(h[n], Cv[n], y);
            }
            yk[((size_t)b * L_ + lm_cur) * Dn + d] = f2bf(fmaf(Dk, u, y));
        }
    }
}

// ---------------- merge 4 dirs + LayerNorm(Dn) * SiLU(z) -> bf16 ------------
// one wave per row; block = 4 waves = 4 rows
__global__ __launch_bounds__(256) void k_ln(const short* __restrict__ y0,
                                            const short* __restrict__ y1,
                                            const short* __restrict__ y2,
                                            const short* __restrict__ y3,
                                            const short* __restrict__ zb,
                                            const float* __restrict__ lnw,
                                            const float* __restrict__ lnb,
                                            short* __restrict__ yfin) {
    const int row = blockIdx.x * 4 + (threadIdx.x >> 6);
    const int lane = threadIdx.x & 63;
    const size_t base = (size_t)row * Dn;
    float v[3];
    float s = 0.f, s2 = 0.f;
#pragma unroll
    for (int j = 0; j < 3; j++) {
        size_t idx = base + lane + j * 64;
        v[j] = bf2f(y0[idx]) + bf2f(y1[idx]) + bf2f(y2[idx]) + bf2f(y3[idx]);
        s += v[j];
        s2 = fmaf(v[j], v[j], s2);
    }
#pragma unroll
    for (int o = 1; o < 64; o <<= 1) {
        s += __shfl_xor(s, o);
        s2 += __shfl_xor(s2, o);
    }
    const float inv = 1.f / 192.f;
    float mu = s * inv;
    float var = s2 * inv - mu * mu;
    float rstd = rsqrtf(var + 1e-5f);
#pragma unroll
    for (int j = 0; j < 3; j++) {
        int dd = lane + j * 64;
        size_t idx = base + dd;
        float zz = bf2f(zb[idx]);
        float sig = 1.f / (1.f + __expf(-zz));
        float res = ((v[j] - mu) * rstd * lnw[dd] + lnb[dd]) * (zz * sig);
        yfin[idx] = f2bf(res);
    }
}

// ---------------- launcher ---------------------------------------------------
extern "C" void kernel_launch(void* const* d_in, const int* in_sizes, int n_in,
                              void* d_out, int out_size, void* d_ws, size_t ws_size,
                              hipStream_t stream) {
    const float* x    = (const float*)d_in[0];
    const float* w_in = (const float*)d_in[1];
    const float* cw   = (const float*)d_in[2];
    const float* cb   = (const float*)d_in[3];
    const float* xpw  = (const float*)d_in[4];
    const float* dtw  = (const float*)d_in[5];
    const float* dtb  = (const float*)d_in[6];
    const float* alog = (const float*)d_in[7];
    const float* dvec = (const float*)d_in[8];
    const float* lnw  = (const float*)d_in[9];
    const float* lnb  = (const float*)d_in[10];
    const float* wout = (const float*)d_in[11];
    float* out = (float*)d_out;

    const size_t SH  = (size_t)MROWS * Dn;               // 6,291,456 elems
    const size_t SCN = (size_t)B_ * K_ * NC * Dn * Nst;  // 3,145,728 elems

    char* p = (char*)d_ws;
    short* x_bf  = (short*)p; p += SH * 2;               // region0 -> y0
    short* xf_bf = (short*)p; p += SH * 2;               // region1 -> y1
    short* z_bf  = (short*)p; p += SH * 2;               // region2
    short* xc_bf = (short*)p; p += SH * 2;               // region3
    float* xdbl  = (float*)p; p += (size_t)MROWS * (K_ * CPROJ) * 4;
    float* Aprod = (float*)p; p += SCN * 4;              // region5 -> y2
    float* hpart = (float*)p; p += SCN * 4;              // region6 -> y3
    float* hin   = (float*)p; p += SCN * 4;              // region7 -> yfin
    short* w_bf  = (short*)p;
    // aliases (lifetimes): y0<-x_bf (dead after in_proj), y1<-xf_bf (dead after
    // conv), y2<-Aprod, y3<-hpart (dead after scan2), yfin<-hin (dead after
    // scan3; k_ln runs after scan3).
    short* y0 = x_bf;
    short* y1 = xf_bf;
    short* y2 = (short*)Aprod;
    short* y3 = (short*)hpart;
    short* yfin_bf = (short*)hin;

    // 0. fused converts
    k_cvt<<<(XUNITS + WUNITS + 255) / 256, 256, 0, stream>>>(x, w_in, xpw, wout,
                                                             x_bf, w_bf);
    // 1. in_proj (MFMA) -> xf_bf, z_bf
    k_mgemm_in<<<dim3(MROWS / 128, 6), 256, 0, stream>>>(x_bf, w_bf + WOFF_IN,
                                                         xf_bf, z_bf, C_);
    // 2. depthwise conv 3x3 + SiLU -> xc_bf
    k_conv<<<(int)(SH / 256), 256, 0, stream>>>(xf_bf, cw, cb, xc_bf);
    // 3. x_dbl (all 4 dirs, one MFMA GEMM) -> f32
    k_mgemm_f<<<dim3(MROWS / 128, 2), 256, 0, stream>>>(xc_bf, w_bf + WOFF_XP,
                                                        xdbl, K_ * CPROJ, Dn);
    // 4-6. chunked parallel selective scan
    k_scan1<<<B_ * K_ * NC, 192, 0, stream>>>(xc_bf, xdbl, dtw, dtb, alog, Aprod, hpart);
    k_scan2<<<(B_ * K_ * Dn * Nst) / 256, 256, 0, stream>>>(Aprod, hpart, hin);
    k_scan3<<<B_ * K_ * NC, 192, 0, stream>>>(xc_bf, xdbl, dtw, dtb, alog, dvec,
                                              hin, y0, y1, y2, y3);
    // 7. merge + LayerNorm * SiLU(z) -> bf16
    k_ln<<<MROWS / 4, 256, 0, stream>>>(y0, y1, y2, y3, z_bf, lnw, lnb, yfin_bf);
    // 8. out_proj (MFMA) -> d_out (f32)
    k_mgemm_f<<<dim3(MROWS / 128, 3), 256, 0, stream>>>(yfin_bf, w_bf + WOFF_OUT,
                                                        out, C_, Dn);
}

// Round 5
// 237.677 us; speedup vs baseline: 1.0599x; 1.0599x over previous
//
#include <hip/hip_runtime.h>
#include <hip/hip_bf16.h>

// ---------------- problem constants (fixed by setup_inputs) ----------------
constexpr int B_  = 8;
constexpr int H_  = 64;
constexpr int W_  = 64;
constexpr int C_  = 192;
constexpr int Dn  = 192;
constexpr int Nst = 8;    // state dim N
constexpr int R_  = 12;
constexpr int K_  = 4;    // directions
constexpr int L_  = H_ * W_;          // 4096
constexpr int CS  = 32;               // scan chunk size (r5: 64->32 for 2x TLP)
constexpr int NC  = L_ / CS;          // 128 chunks
constexpr int CPROJ = R_ + 2 * Nst;   // 28 proj outputs per direction
constexpr int MROWS = B_ * L_;        // 32768

typedef __attribute__((ext_vector_type(8))) short short8v;
typedef __attribute__((ext_vector_type(4))) float f32x4;

// t -> spatial position for direction k (verified round 0).
// Within a chunk [t0, t0+CS) with CS|64: lm = map_t(k,t0) + ts*stride,
// stride = ((k&1)?64:1) * ((k>=2)?-1:1)  (no &63 wraparound since CS<=64).
__device__ __forceinline__ int map_t(int k, int t) {
    int tt = (k >= 2) ? (L_ - 1 - t) : t;
    if (k & 1) tt = (tt & 63) * 64 + (tt >> 6);
    return tt;
}

__device__ __forceinline__ short f2bf(float f) {   // round-to-nearest-even
    unsigned u = __float_as_uint(f);
    u += 0x7FFFu + ((u >> 16) & 1u);
    return (short)(u >> 16);
}
__device__ __forceinline__ float bf2f(short s) {
    return __uint_as_float(((unsigned)(unsigned short)s) << 16);
}

// ---------------- fused f32 -> bf16 convert (x and all weights) -------------
constexpr int WOFF_IN  = 0;               // w_in  (384x192)
constexpr int WOFF_XP  = 73728;           // xpw   (112x192)
constexpr int WOFF_OUT = 95232;           // wout  (192x192)
constexpr int WTOTAL   = 132096;
constexpr int XUNITS   = MROWS * Dn / 8;  // 786432 groups of 8
constexpr int WUNITS   = WTOTAL / 8;      // 16512
__global__ __launch_bounds__(256) void k_cvt(const float* __restrict__ x,
                                             const float* __restrict__ w_in,
                                             const float* __restrict__ xpw,
                                             const float* __restrict__ wout,
                                             short* __restrict__ x_bf,
                                             short* __restrict__ w_bf) {
    int g = blockIdx.x * 256 + threadIdx.x;
    const float* src;
    short* dst;
    int off;
    if (g < XUNITS) { src = x; dst = x_bf; off = g * 8; }
    else {
        g -= XUNITS;
        if (g >= WUNITS) return;
        int base = g * 8;
        dst = w_bf; off = base;
        if (base < WOFF_XP)       { src = w_in; }
        else if (base < WOFF_OUT) { src = xpw;  src -= WOFF_XP; }
        else                      { src = wout; src -= WOFF_OUT; }
    }
    float4 a = *reinterpret_cast<const float4*>(src + off);
    float4 b = *reinterpret_cast<const float4*>(src + off + 4);
    short8v v = {f2bf(a.x), f2bf(a.y), f2bf(a.z), f2bf(a.w),
                 f2bf(b.x), f2bf(b.y), f2bf(b.z), f2bf(b.w)};
    *reinterpret_cast<short8v*>(dst + off) = v;
}

// ---------------- bf16 MFMA GEMM cores --------------------------------------
__device__ __forceinline__ void mgemm_core(const short* __restrict__ A,
                                           const short* __restrict__ Wb,
                                           f32x4 (&acc)[4][2],
                                           int mrow, int ncol, int Nact, int K) {
    const int lane = threadIdx.x & 63;
    const int koff = (lane >> 4) * 8;
    for (int k0 = 0; k0 < K; k0 += 32) {
        short8v af[4], bfr[2];
#pragma unroll
        for (int mf = 0; mf < 4; mf++)
            af[mf] = *reinterpret_cast<const short8v*>(
                A + (size_t)(mrow + mf * 16) * K + k0 + koff);
#pragma unroll
        for (int nf = 0; nf < 2; nf++) {
            int r = ncol + nf * 16;
            short8v z = {0, 0, 0, 0, 0, 0, 0, 0};
            bfr[nf] = (r < Nact)
                ? *reinterpret_cast<const short8v*>(Wb + (size_t)r * K + k0 + koff)
                : z;
        }
#pragma unroll
        for (int mf = 0; mf < 4; mf++)
#pragma unroll
            for (int nf = 0; nf < 2; nf++)
                acc[mf][nf] = __builtin_amdgcn_mfma_f32_16x16x32_bf16(
                    af[mf], bfr[nf], acc[mf][nf], 0, 0, 0);
    }
}

// f32-output GEMM (x_proj, out_proj)
__global__ __launch_bounds__(256) void k_mgemm_f(const short* __restrict__ A,
                                                 const short* __restrict__ Wb,
                                                 float* __restrict__ out0,
                                                 int Nact, int K) {
    const int m0 = blockIdx.x * 128, n0 = blockIdx.y * 64;
    const int wid = threadIdx.x >> 6, lane = threadIdx.x & 63;
    const int wm = wid >> 1, wn = wid & 1;
    f32x4 acc[4][2] = {};
    mgemm_core(A, Wb, acc, m0 + wm * 64 + (lane & 15), n0 + wn * 32 + (lane & 15),
               Nact, K);
    const int prow = (lane >> 4) * 4, pcol = lane & 15;
#pragma unroll
    for (int mf = 0; mf < 4; mf++) {
        int mbase = m0 + wm * 64 + mf * 16 + prow;
#pragma unroll
        for (int nf = 0; nf < 2; nf++) {
            int n = n0 + wn * 32 + nf * 16 + pcol;
            if (n >= Nact) continue;
#pragma unroll
            for (int r = 0; r < 4; r++)
                out0[(size_t)(mbase + r) * Nact + n] = acc[mf][nf][r];
        }
    }
}

// in_proj: split bf16 outputs (xf | z), each ldc=192
__global__ __launch_bounds__(256) void k_mgemm_in(const short* __restrict__ A,
                                                  const short* __restrict__ Wb,
                                                  short* __restrict__ xf_bf,
                                                  short* __restrict__ z_bf,
                                                  int K) {
    const int m0 = blockIdx.x * 128, n0 = blockIdx.y * 64;
    const int wid = threadIdx.x >> 6, lane = threadIdx.x & 63;
    const int wm = wid >> 1, wn = wid & 1;
    f32x4 acc[4][2] = {};
    mgemm_core(A, Wb, acc, m0 + wm * 64 + (lane & 15), n0 + wn * 32 + (lane & 15),
               384, K);
    const int prow = (lane >> 4) * 4, pcol = lane & 15;
#pragma unroll
    for (int mf = 0; mf < 4; mf++) {
        int mbase = m0 + wm * 64 + mf * 16 + prow;
#pragma unroll
        for (int nf = 0; nf < 2; nf++) {
            int n = n0 + wn * 32 + nf * 16 + pcol;
#pragma unroll
            for (int r = 0; r < 4; r++) {
                int m = mbase + r;
                if (n < 192) xf_bf[(size_t)m * 192 + n] = f2bf(acc[mf][nf][r]);
                else         z_bf[(size_t)m * 192 + (n - 192)] = f2bf(acc[mf][nf][r]);
            }
        }
    }
}

// ---------------- depthwise 3x3 conv + bias + SiLU (bf16 in/out) ------------
__global__ __launch_bounds__(256) void k_conv(const short* __restrict__ xfb,
                                              const float* __restrict__ cw,
                                              const float* __restrict__ cb,
                                              short* __restrict__ xcb) {
    size_t i = (size_t)blockIdx.x * 256 + threadIdx.x;  // over B*H*W*Dn
    int d = (int)(i % Dn);
    int p = (int)(i / Dn);
    int w = p & 63; p >>= 6;
    int h = p & 63; p >>= 6;
    int b = p;
    float acc = cb[d];
#pragma unroll
    for (int kh = 0; kh < 3; kh++) {
        int hh = h + kh - 1;
        if (hh < 0 || hh >= H_) continue;
#pragma unroll
        for (int kw = 0; kw < 3; kw++) {
            int ww = w + kw - 1;
            if (ww < 0 || ww >= W_) continue;
            acc = fmaf(bf2f(xfb[(((size_t)b * H_ + hh) * W_ + ww) * Dn + d]),
                       cw[d * 9 + kh * 3 + kw], acc);
        }
    }
    float sig = 1.f / (1.f + __expf(-acc));
    xcb[i] = f2bf(acc * sig);
}

// ---------------- per-step delta / e1 helper --------------------------------
// x = dt pre-activation. delta = softplus(x); e1 = exp(-delta) = 1/(1+e^x).
__device__ __forceinline__ void delta_e1(float x, float& delta, float& e1) {
    if (x > 20.f) { delta = x; e1 = __expf(-x); }
    else {
        float t = __expf(x);
        delta = __logf(1.f + t);
        e1 = __builtin_amdgcn_rcpf(1.f + t);
    }
}

__device__ __forceinline__ float dot12(const float4& a, const float4& b,
                                       const float4& c, const float* w, float x) {
    x = fmaf(a.x, w[0], x);  x = fmaf(a.y, w[1], x);
    x = fmaf(a.z, w[2], x);  x = fmaf(a.w, w[3], x);
    x = fmaf(b.x, w[4], x);  x = fmaf(b.y, w[5], x);
    x = fmaf(b.z, w[6], x);  x = fmaf(b.w, w[7], x);
    x = fmaf(c.x, w[8], x);  x = fmaf(c.y, w[9], x);
    x = fmaf(c.z, w[10], x); x = fmaf(c.w, w[11], x);
    return x;
}

// ---------------- scan phase 1: per-chunk (prod(a), h_partial) --------------
// LDS holds per-step [dt(12) | B(8)] = 5 float4 (C not consumed here).
__global__ __launch_bounds__(192) void k_scan1(const short* __restrict__ xcb,
                                               const float* __restrict__ xdbl,
                                               const float* __restrict__ dtw_all,
                                               const float* __restrict__ dtb_all,
                                               const float* __restrict__ alog,
                                               float* __restrict__ Aprod,
                                               float* __restrict__ hpart) {
    const int blk = blockIdx.x;            // ((b*K + k)*NC + c)
    const int c = blk % NC;
    const int k = (blk / NC) % K_;
    const int b = blk / (NC * K_);
    const int d = threadIdx.x;
    const int t0 = c * CS;
    const int stride = ((k & 1) ? 64 : 1) * ((k >= 2) ? -1 : 1);
    const int lm0 = map_t(k, t0);

    __shared__ float4 sx4[CS][5];
    const float4* xd4 = reinterpret_cast<const float4*>(xdbl);
    for (int i = d; i < CS * 5; i += 192) {
        int ts = i / 5, q = i % 5;
        sx4[ts][q] = xd4[((size_t)b * L_ + lm0 + ts * stride) * 28 + k * 7 + q];
    }
    __syncthreads();

    float dtw[R_];
#pragma unroll
    for (int r = 0; r < R_; r++) dtw[r] = dtw_all[((size_t)k * Dn + d) * R_ + r];
    const float bias = dtb_all[k * Dn + d];
    float Av[Nst];
    bool fast = true;
#pragma unroll
    for (int n = 0; n < Nst; n++) {
        Av[n] = -__expf(alog[((size_t)k * Dn + d) * Nst + n]);
        fast = fast && (fabsf(Av[n] + (float)(n + 1)) < 1e-3f);
    }

    float h[Nst] = {};
    float Ap[Nst];
#pragma unroll
    for (int n = 0; n < Nst; n++) Ap[n] = 1.f;
    float e1p = 1.f;

    const long stepD = (long)stride * Dn;
    const short* up = xcb + ((size_t)b * L_ + lm0) * Dn + d;
    float u_next = bf2f(*up);
    if (fast) {
        for (int ts = 0; ts < CS; ts++) {
            float u = u_next;
            up += stepD;
            if (ts + 1 < CS) u_next = bf2f(*up);
            float4 q0 = sx4[ts][0], q1 = sx4[ts][1], q2 = sx4[ts][2];
            float4 qb0 = sx4[ts][3], qb1 = sx4[ts][4];
            float delta, e1; delta_e1(dot12(q0, q1, q2, dtw, bias), delta, e1);
            float du = delta * u;
            e1p *= e1;
            float a2 = e1 * e1, a3 = a2 * e1, a4 = a2 * a2;
            float a5 = a4 * e1, a6 = a4 * a2, a7 = a4 * a3, a8 = a4 * a4;
            h[0] = fmaf(e1, h[0], du * qb0.x);
            h[1] = fmaf(a2, h[1], du * qb0.y);
            h[2] = fmaf(a3, h[2], du * qb0.z);
            h[3] = fmaf(a4, h[3], du * qb0.w);
            h[4] = fmaf(a5, h[4], du * qb1.x);
            h[5] = fmaf(a6, h[5], du * qb1.y);
            h[6] = fmaf(a7, h[6], du * qb1.z);
            h[7] = fmaf(a8, h[7], du * qb1.w);
        }
        float p2 = e1p * e1p, p3 = p2 * e1p, p4 = p2 * p2;
        Ap[0] = e1p; Ap[1] = p2; Ap[2] = p3; Ap[3] = p4;
        Ap[4] = p4 * e1p; Ap[5] = p4 * p2; Ap[6] = p4 * p3; Ap[7] = p4 * p4;
    } else {
        for (int ts = 0; ts < CS; ts++) {
            float u = u_next;
            up += stepD;
            if (ts + 1 < CS) u_next = bf2f(*up);
            float4 q0 = sx4[ts][0], q1 = sx4[ts][1], q2 = sx4[ts][2];
            float4 qb0 = sx4[ts][3], qb1 = sx4[ts][4];
            float Bv[Nst] = {qb0.x, qb0.y, qb0.z, qb0.w, qb1.x, qb1.y, qb1.z, qb1.w};
            float delta, e1; delta_e1(dot12(q0, q1, q2, dtw, bias), delta, e1);
            float du = delta * u;
#pragma unroll
            for (int n = 0; n < Nst; n++) {
                float a = __expf(delta * Av[n]);
                Ap[n] *= a;
                h[n] = fmaf(a, h[n], du * Bv[n]);
            }
        }
    }
    size_t base = ((((size_t)(b * K_ + k) * NC + c) * Dn + d)) * Nst;
#pragma unroll
    for (int n = 0; n < Nst; n++) { Aprod[base + n] = Ap[n]; hpart[base + n] = h[n]; }
}

// ---------------- scan phase 2: chunk-level recurrence -----------------------
__global__ __launch_bounds__(256) void k_scan2(const float* __restrict__ Aprod,
                                               const float* __restrict__ hpart,
                                               float* __restrict__ hin) {
    int idx = blockIdx.x * 256 + threadIdx.x;   // B*K*Dn*Nst = 49152
    int dn = idx % (Dn * Nst);
    int bk = idx / (Dn * Nst);
    size_t stride = (size_t)Dn * Nst;
    size_t base = (size_t)bk * NC * stride + dn;
    float h = 0.f;
    for (int cc = 0; cc < NC; cc++) {
        size_t s = base + (size_t)cc * stride;
        hin[s] = h;
        h = fmaf(Aprod[s], h, hpart[s]);
    }
}

// ---------------- scan phase 3: recompute with h_in, emit y (plain store) ---
// LDS holds per-step [dt(12) | B(8) | C(8)] = 7 float4.
__global__ __launch_bounds__(192) void k_scan3(const short* __restrict__ xcb,
                                               const float* __restrict__ xdbl,
                                               const float* __restrict__ dtw_all,
                                               const float* __restrict__ dtb_all,
                                               const float* __restrict__ alog,
                                               const float* __restrict__ dvec,
                                               const float* __restrict__ hin,
                                               short* __restrict__ y0,
                                               short* __restrict__ y1,
                                               short* __restrict__ y2,
                                               short* __restrict__ y3) {
    const int blk = blockIdx.x;
    const int c = blk % NC;
    const int k = (blk / NC) % K_;
    const int b = blk / (NC * K_);
    const int d = threadIdx.x;
    const int t0 = c * CS;
    const int stride = ((k & 1) ? 64 : 1) * ((k >= 2) ? -1 : 1);
    const int lm0 = map_t(k, t0);
    short* __restrict__ yk = (k == 0) ? y0 : (k == 1) ? y1 : (k == 2) ? y2 : y3;

    __shared__ float4 sx4[CS][7];
    const float4* xd4 = reinterpret_cast<const float4*>(xdbl);
    for (int i = d; i < CS * 7; i += 192) {
        int ts = i / 7, q = i % 7;
        sx4[ts][q] = xd4[((size_t)b * L_ + lm0 + ts * stride) * 28 + k * 7 + q];
    }
    __syncthreads();

    float dtw[R_];
#pragma unroll
    for (int r = 0; r < R_; r++) dtw[r] = dtw_all[((size_t)k * Dn + d) * R_ + r];
    const float bias = dtb_all[k * Dn + d];
    const float Dk = dvec[k * Dn + d];
    float Av[Nst];
    bool fast = true;
#pragma unroll
    for (int n = 0; n < Nst; n++) {
        Av[n] = -__expf(alog[((size_t)k * Dn + d) * Nst + n]);
        fast = fast && (fabsf(Av[n] + (float)(n + 1)) < 1e-3f);
    }

    size_t hbase = ((((size_t)(b * K_ + k) * NC + c) * Dn + d)) * Nst;
    float h[Nst];
#pragma unroll
    for (int n = 0; n < Nst; n++) h[n] = hin[hbase + n];

    const long stepD = (long)stride * Dn;
    const short* up = xcb + ((size_t)b * L_ + lm0) * Dn + d;
    short* yp = yk + ((size_t)b * L_ + lm0) * Dn + d;
    float u_next = bf2f(*up);
    if (fast) {
        for (int ts = 0; ts < CS; ts++) {
            float u = u_next;
            up += stepD;
            if (ts + 1 < CS) u_next = bf2f(*up);
            float4 q0 = sx4[ts][0], q1 = sx4[ts][1], q2 = sx4[ts][2];
            float4 qb0 = sx4[ts][3], qb1 = sx4[ts][4];
            float4 qc0 = sx4[ts][5], qc1 = sx4[ts][6];
            float delta, e1; delta_e1(dot12(q0, q1, q2, dtw, bias), delta, e1);
            float du = delta * u;
            float a2 = e1 * e1, a3 = a2 * e1, a4 = a2 * a2;
            float a5 = a4 * e1, a6 = a4 * a2, a7 = a4 * a3, a8 = a4 * a4;
            h[0] = fmaf(e1, h[0], du * qb0.x);
            h[1] = fmaf(a2, h[1], du * qb0.y);
            h[2] = fmaf(a3, h[2], du * qb0.z);
            h[3] = fmaf(a4, h[3], du * qb0.w);
            h[4] = fmaf(a5, h[4], du * qb1.x);
            h[5] = fmaf(a6, h[5], du * qb1.y);
            h[6] = fmaf(a7, h[6], du * qb1.z);
            h[7] = fmaf(a8, h[7], du * qb1.w);
            float y = h[0] * qc0.x;
            y = fmaf(h[1], qc0.y, y);
            y = fmaf(h[2], qc0.z, y);
            y = fmaf(h[3], qc0.w, y);
            y = fmaf(h[4], qc1.x, y);
            y = fmaf(h[5], qc1.y, y);
            y = fmaf(h[6], qc1.z, y);
            y = fmaf(h[7], qc1.w, y);
            *yp = f2bf(fmaf(Dk, u, y));
            yp += stepD;
        }
    } else {
        for (int ts = 0; ts < CS; ts++) {
            float u = u_next;
            up += stepD;
            if (ts + 1 < CS) u_next = bf2f(*up);
            float4 q0 = sx4[ts][0], q1 = sx4[ts][1], q2 = sx4[ts][2];
            float4 qb0 = sx4[ts][3], qb1 = sx4[ts][4];
            float4 qc0 = sx4[ts][5], qc1 = sx4[ts][6];
            float Bv[Nst] = {qb0.x, qb0.y, qb0.z, qb0.w, qb1.x, qb1.y, qb1.z, qb1.w};
            float Cv[Nst] = {qc0.x, qc0.y, qc0.z, qc0.w, qc1.x, qc1.y, qc1.z, qc1.w};
            float delta, e1; delta_e1(dot12(q0, q1, q2, dtw, bias), delta, e1);
            float du = delta * u;
            float y = 0.f;
#pragma unroll
            for (int n = 0; n < Nst; n++) {
                float a = __expf(delta * Av[n]);
                h[n] = fmaf(a, h[n], du * Bv[n]);
                y = fmaf(h[n], Cv[n], y);
            }
            *yp = f2bf(fmaf(Dk, u, y));
            yp += stepD;
        }
    }
}

// ---------------- merge 4 dirs + LayerNorm(Dn) * SiLU(z) -> bf16 ------------
// one wave per row; block = 4 waves = 4 rows
__global__ __launch_bounds__(256) void k_ln(const short* __restrict__ y0,
                                            const short* __restrict__ y1,
                                            const short* __restrict__ y2,
                                            const short* __restrict__ y3,
                                            const short* __restrict__ zb,
                                            const float* __restrict__ lnw,
                                            const float* __restrict__ lnb,
                                            short* __restrict__ yfin) {
    const int row = blockIdx.x * 4 + (threadIdx.x >> 6);
    const int lane = threadIdx.x & 63;
    const size_t base = (size_t)row * Dn;
    float v[3];
    float s = 0.f, s2 = 0.f;
#pragma unroll
    for (int j = 0; j < 3; j++) {
        size_t idx = base + lane + j * 64;
        v[j] = bf2f(y0[idx]) + bf2f(y1[idx]) + bf2f(y2[idx]) + bf2f(y3[idx]);
        s += v[j];
        s2 = fmaf(v[j], v[j], s2);
    }
#pragma unroll
    for (int o = 1; o < 64; o <<= 1) {
        s += __shfl_xor(s, o);
        s2 += __shfl_xor(s2, o);
    }
    const float inv = 1.f / 192.f;
    float mu = s * inv;
    float var = s2 * inv - mu * mu;
    float rstd = rsqrtf(var + 1e-5f);
#pragma unroll
    for (int j = 0; j < 3; j++) {
        int dd = lane + j * 64;
        size_t idx = base + dd;
        float zz = bf2f(zb[idx]);
        float sig = 1.f / (1.f + __expf(-zz));
        float res = ((v[j] - mu) * rstd * lnw[dd] + lnb[dd]) * (zz * sig);
        yfin[idx] = f2bf(res);
    }
}

// ---------------- launcher ---------------------------------------------------
extern "C" void kernel_launch(void* const* d_in, const int* in_sizes, int n_in,
                              void* d_out, int out_size, void* d_ws, size_t ws_size,
                              hipStream_t stream) {
    const float* x    = (const float*)d_in[0];
    const float* w_in = (const float*)d_in[1];
    const float* cw   = (const float*)d_in[2];
    const float* cb   = (const float*)d_in[3];
    const float* xpw  = (const float*)d_in[4];
    const float* dtw  = (const float*)d_in[5];
    const float* dtb  = (const float*)d_in[6];
    const float* alog = (const float*)d_in[7];
    const float* dvec = (const float*)d_in[8];
    const float* lnw  = (const float*)d_in[9];
    const float* lnb  = (const float*)d_in[10];
    const float* wout = (const float*)d_in[11];
    float* out = (float*)d_out;

    const size_t SH  = (size_t)MROWS * Dn;               // 6,291,456 elems
    const size_t SCN = (size_t)B_ * K_ * NC * Dn * Nst;  // 6,291,456 elems

    char* p = (char*)d_ws;
    short* x_bf  = (short*)p; p += SH * 2;               // region0 -> y0
    short* xf_bf = (short*)p; p += SH * 2;               // region1 -> y1
    short* z_bf  = (short*)p; p += SH * 2;               // region2
    short* xc_bf = (short*)p; p += SH * 2;               // region3
    float* xdbl  = (float*)p; p += (size_t)MROWS * (K_ * CPROJ) * 4;
    float* Aprod = (float*)p; p += SCN * 4;              // region5 -> y2
    float* hpart = (float*)p; p += SCN * 4;              // region6 -> y3
    float* hin   = (float*)p; p += SCN * 4;              // region7 -> yfin
    short* w_bf  = (short*)p;
    // aliases (lifetimes): y0<-x_bf (dead after in_proj), y1<-xf_bf (dead after
    // conv), y2<-Aprod, y3<-hpart (dead after scan2), yfin<-hin (dead after
    // scan3; k_ln runs after scan3).
    short* y0 = x_bf;
    short* y1 = xf_bf;
    short* y2 = (short*)Aprod;
    short* y3 = (short*)hpart;
    short* yfin_bf = (short*)hin;

    // 0. fused converts
    k_cvt<<<(XUNITS + WUNITS + 255) / 256, 256, 0, stream>>>(x, w_in, xpw, wout,
                                                             x_bf, w_bf);
    // 1. in_proj (MFMA) -> xf_bf, z_bf
    k_mgemm_in<<<dim3(MROWS / 128, 6), 256, 0, stream>>>(x_bf, w_bf + WOFF_IN,
                                                         xf_bf, z_bf, C_);
    // 2. depthwise conv 3x3 + SiLU -> xc_bf
    k_conv<<<(int)(SH / 256), 256, 0, stream>>>(xf_bf, cw, cb, xc_bf);
    // 3. x_dbl (all 4 dirs, one MFMA GEMM) -> f32
    k_mgemm_f<<<dim3(MROWS / 128, 2), 256, 0, stream>>>(xc_bf, w_bf + WOFF_XP,
                                                        xdbl, K_ * CPROJ, Dn);
    // 4-6. chunked parallel selective scan (CS=32: 4096 blocks for TLP)
    k_scan1<<<B_ * K_ * NC, 192, 0, stream>>>(xc_bf, xdbl, dtw, dtb, alog, Aprod, hpart);
    k_scan2<<<(B_ * K_ * Dn * Nst) / 256, 256, 0, stream>>>(Aprod, hpart, hin);
    k_scan3<<<B_ * K_ * NC, 192, 0, stream>>>(xc_bf, xdbl, dtw, dtb, alog, dvec,
                                              hin, y0, y1, y2, y3);
    // 7. merge + LayerNorm * SiLU(z) -> bf16
    k_ln<<<MROWS / 4, 256, 0, stream>>>(y0, y1, y2, y3, z_bf, lnw, lnb, yfin_bf);
    // 8. out_proj (MFMA) -> d_out (f32)
    k_mgemm_f<<<dim3(MROWS / 128, 3), 256, 0, stream>>>(yfin_bf, w_bf + WOFF_OUT,
                                                        out, C_, Dn);
}